// Round 7
// baseline (4312.116 us; speedup 1.0000x reference)
//
#include <hip/hip_runtime.h>
#include <hip/hip_bf16.h>

#define B_ 32
#define T_ 2000
#define S_ 400
#define C0_ 80
#define H_ 256

static constexpr float NEGV = -1e9f;
static constexpr int NMU  = B_ * T_ * S_;       // 25,600,000
static constexpr int NPI  = 2 * NMU;            // 51,200,000
static constexpr int NWSP = B_ * T_ * H_;       // 16,384,000

// ---------------- conv1d (K=5, SAME) + bias + tanh ----------------------
template<int CIN>
__global__ __launch_bounds__(256)
void conv1d_tanh(const float* __restrict__ x, const float* __restrict__ w,
                 const float* __restrict__ bias, float* __restrict__ y)
{
  constexpr int TT  = 32;        // t rows per block
  constexpr int JW  = TT + 4;    // halo rows (pad 2 each side)
  constexpr int STR = 40;        // padded LDS stride
  __shared__ float xs[CIN * STR];
  const int b   = blockIdx.y;
  const int t0  = blockIdx.x * TT;
  const int tid = threadIdx.x;
  const float* xb = x + (size_t)b * T_ * CIN;
  for (int idx = tid; idx < JW * CIN; idx += 256) {
    int ci = idx % CIN;
    int j  = idx / CIN;
    int t  = t0 - 2 + j;
    xs[ci * STR + j] = (t >= 0 && t < T_) ? xb[(size_t)t * CIN + ci] : 0.f;
  }
  __syncthreads();
  const int co = tid;
  float acc[TT];
#pragma unroll
  for (int i = 0; i < TT; i++) acc[i] = 0.f;
  for (int ci = 0; ci < CIN; ci++) {
    float xv[JW];
    const float4* xp = (const float4*)&xs[ci * STR];
#pragma unroll
    for (int r = 0; r < JW / 4; r++) {
      float4 q = xp[r];
      xv[4*r+0] = q.x; xv[4*r+1] = q.y; xv[4*r+2] = q.z; xv[4*r+3] = q.w;
    }
#pragma unroll
    for (int k = 0; k < 5; k++) {
      float wv = w[((size_t)k * CIN + ci) * H_ + co];
#pragma unroll
      for (int i = 0; i < TT; i++) acc[i] = fmaf(xv[i + k], wv, acc[i]);
    }
  }
  const float bv = bias[co];
#pragma unroll
  for (int i = 0; i < TT; i++) {
    int t = t0 + i;
    if (t < T_) y[((size_t)b * T_ + t) * H_ + co] = tanhf(acc[i] + bv);
  }
}

// ---------------- W[b,t,s] = sum_h Wspec[b,t,h] * src_enc[b,s,h] --------
__global__ __launch_bounds__(256)
void einsum_ts(const float* __restrict__ A, const float* __restrict__ E,
               float* __restrict__ Wg)
{
  constexpr int GT = 128, GS = 64, KC = 16;
  __shared__ float As[KC][GT + 4];
  __shared__ float Bs[KC][GS + 4];
  const int b   = blockIdx.z;
  const int t0  = blockIdx.x * GT;
  const int s0  = blockIdx.y * GS;
  const int tid = threadIdx.x;
  const int tx  = tid & 15;
  const int ty  = tid >> 4;
  float4 acc[8];
#pragma unroll
  for (int i = 0; i < 8; i++) acc[i] = make_float4(0.f, 0.f, 0.f, 0.f);
  const float* Ab = A + (size_t)b * T_ * H_;
  const float* Eb = E + (size_t)b * S_ * H_;
  for (int kc = 0; kc < H_; kc += KC) {
#pragma unroll
    for (int r = 0; r < 2; r++) {
      int f4  = tid + 256 * r;
      int row = f4 >> 2;
      int c4  = f4 & 3;
      int t   = t0 + row;
      float4 v = make_float4(0, 0, 0, 0);
      if (t < T_) v = *(const float4*)&Ab[(size_t)t * H_ + kc + c4 * 4];
      As[c4*4+0][row] = v.x; As[c4*4+1][row] = v.y;
      As[c4*4+2][row] = v.z; As[c4*4+3][row] = v.w;
    }
    {
      int row = tid >> 2;
      int c4  = tid & 3;
      int s   = s0 + row;
      float4 v = make_float4(0, 0, 0, 0);
      if (s < S_) v = *(const float4*)&Eb[(size_t)s * H_ + kc + c4 * 4];
      Bs[c4*4+0][row] = v.x; Bs[c4*4+1][row] = v.y;
      Bs[c4*4+2][row] = v.z; Bs[c4*4+3][row] = v.w;
    }
    __syncthreads();
#pragma unroll
    for (int kk = 0; kk < KC; kk++) {
      float4 a0 = *(const float4*)&As[kk][ty * 8];
      float4 a1 = *(const float4*)&As[kk][ty * 8 + 4];
      float4 bb = *(const float4*)&Bs[kk][tx * 4];
      float av[8] = {a0.x, a0.y, a0.z, a0.w, a1.x, a1.y, a1.z, a1.w};
#pragma unroll
      for (int i = 0; i < 8; i++) {
        acc[i].x = fmaf(av[i], bb.x, acc[i].x);
        acc[i].y = fmaf(av[i], bb.y, acc[i].y);
        acc[i].z = fmaf(av[i], bb.z, acc[i].z);
        acc[i].w = fmaf(av[i], bb.w, acc[i].w);
      }
    }
    __syncthreads();
  }
  float* Wb = Wg + (size_t)b * T_ * S_;
  const int s = s0 + tx * 4;
#pragma unroll
  for (int i = 0; i < 8; i++) {
    int t = t0 + ty * 8 + i;
    if (t < T_ && s < S_) *(float4*)&Wb[(size_t)t * S_ + s] = acc[i];
  }
}

// ---------------- per-(b,s) column softmax stats over T ------------------
// Writes M + ln(L) into mu[b][0][s] (consumed then overwritten by dp).
__global__ __launch_bounds__(256)
void softmax_stats(const float* __restrict__ Wg, float* __restrict__ statsOut)
{
  const int b  = blockIdx.y;
  const int tx = threadIdx.x & 63;
  const int ty = threadIdx.x >> 6;            // 0..3
  const int s  = blockIdx.x * 64 + tx;
  const bool act = (s < S_);
  float m = -1e30f, l = 0.f;
  if (act) {
    const float* col = Wg + (size_t)b * T_ * S_ + s;
#pragma unroll 4
    for (int t = ty; t < T_; t += 4) {
      float v  = col[(size_t)t * S_];
      float nm = fmaxf(m, v);
      l = l * __expf(m - nm) + __expf(v - nm);
      m = nm;
    }
  }
  __shared__ float rm[4][64], rl[4][64];
  rm[ty][tx] = m; rl[ty][tx] = l;
  __syncthreads();
  if (ty == 0 && act) {
    float M = rm[0][tx];
#pragma unroll
    for (int q = 1; q < 4; q++) M = fmaxf(M, rm[q][tx]);
    float L = 0.f;
#pragma unroll
    for (int q = 0; q < 4; q++) L += rl[q][tx] * __expf(rm[q][tx] - M);
    float* st = statsOut + (size_t)b * T_ * S_;
    st[s] = M + __logf(L);                    // single fused stat
  }
}

// ---------------- alignment normalize + mask premultiply -----------------
// al_out = exp(raw - stat);  Wdp = al_out * mask  (Wdp -> pi-region scratch)
__global__ __launch_bounds__(256)
void norm_kernel(float* __restrict__ al,           // in: raw scores; out: alignments
                 const float* __restrict__ Mk,     // mask
                 const float* __restrict__ muStat, // [B,T,S]; row 0 = M+lnL
                 float* __restrict__ Wdp)          // [B,T,S] scratch
{
  const int gid = blockIdx.x * 256 + threadIdx.x;   // one float4 per thread
  if (gid >= NMU / 4) return;
  const int b   = gid / (T_ * S_ / 4);
  const int rem = gid - b * (T_ * S_ / 4);
  const int s4  = rem % (S_ / 4);
  const float4 st4 = *(const float4*)&muStat[(size_t)b * T_ * S_ + 4 * s4];
  float4 r = ((const float4*)al)[gid];
  float4 k = ((const float4*)Mk)[gid];
  float4 a;
  a.x = __expf(r.x - st4.x);
  a.y = __expf(r.y - st4.y);
  a.z = __expf(r.z - st4.z);
  a.w = __expf(r.w - st4.w);
  ((float4*)al)[gid]  = a;
  ((float4*)Wdp)[gid] = make_float4(a.x * k.x, a.y * k.y, a.z * k.z, a.w * k.w);
}

// ---------------- monotonic-alignment DP: TLP-packed (16 waves/block) ----
// One wave per batch, 16 waves per block, 2 blocks -> 4 waves/SIMD so other
// waves' VALU issue hides each wave's row-load latency. Per-wave code is the
// round-4 known-good dp_mu body: lane l owns s=8l..8l+7, one __shfl_up per
// t-step, no barriers, no LDS.
__global__ __launch_bounds__(1024, 4)
void dp_mu4(const float* __restrict__ Wdp,   // [B,T,S] = alignments * mask
            float* __restrict__ muOut)       // [B,T,S]
{
  const int b = blockIdx.x * 16 + (threadIdx.x >> 6);
  const int l = threadIdx.x & 63;              // lane in wave
  const int s0raw = l * 8;
  const bool act = (s0raw < S_);               // lanes 0..49
  const int c0 = act ? s0raw : (S_ - 8);

  const float* wb  = Wdp   + (size_t)b * T_ * S_;
  float*       mub = muOut + (size_t)b * T_ * S_;

  float m[8];
  // ---- t = 0 ----
  {
    float4 lo = *(const float4*)&wb[c0];
    float4 hi = *(const float4*)&wb[c0 + 4];
    float w0[8] = {lo.x,lo.y,lo.z,lo.w,hi.x,hi.y,hi.z,hi.w};
#pragma unroll
    for (int j = 0; j < 8; j++) m[j] = w0[j] + ((c0 + j) == 0 ? 0.f : NEGV);
    if (act) {
      *(float4*)&mub[c0]     = make_float4(m[0],m[1],m[2],m[3]);
      *(float4*)&mub[c0 + 4] = make_float4(m[4],m[5],m[6],m[7]);
    }
  }

  float4 wL[4], wH[4];

#define LOADW(slot, row)                                                    \
  { const float* r_ = wb + (size_t)(row) * S_ + c0;                         \
    wL[slot] = *(const float4*)r_;  wH[slot] = *(const float4*)(r_ + 4); }

#define DPSTEP(slot, t, prow, doPF)                                         \
  { float wj[8] = {wL[slot].x,wL[slot].y,wL[slot].z,wL[slot].w,             \
                   wH[slot].x,wH[slot].y,wH[slot].z,wH[slot].w};            \
    if (doPF) LOADW(slot, prow)                                             \
    float sh = __shfl_up(m[7], 1);                                          \
    if (l == 0) sh = NEGV;                                                  \
    _Pragma("unroll")                                                       \
    for (int j = 7; j >= 0; j--) {                                          \
      float prev = m[j];                                                    \
      float sft  = (j == 0) ? sh : m[j - 1];                                \
      float d    = prev - sft;                                              \
      float e    = __expf(-fabsf(d));                                       \
      float lg   = __logf(1.f + e);                                         \
      float hi   = fmaxf(prev, sft);                                        \
      m[j] = wj[j] + hi + lg;                                               \
    }                                                                       \
    if (act) {                                                              \
      float* wm_ = mub + (size_t)(t) * S_ + c0;                             \
      *(float4*)wm_       = make_float4(m[0],m[1],m[2],m[3]);               \
      *(float4*)(wm_ + 4) = make_float4(m[4],m[5],m[6],m[7]);               \
    } }

  // initial prefetch: rows 1..4 into slots 0..3
  LOADW(0, 1) LOADW(1, 2) LOADW(2, 3) LOADW(3, 4)

  int t0 = 1;
  for (; t0 + 7 <= T_ - 1; t0 += 4) {
    DPSTEP(0, t0 + 0, t0 + 4, true)
    DPSTEP(1, t0 + 1, t0 + 5, true)
    DPSTEP(2, t0 + 2, t0 + 6, true)
    DPSTEP(3, t0 + 3, t0 + 7, true)
  }
  // t0 == 1993: slots hold rows 1993..1996; rows 1997..1999 still to load
  DPSTEP(0, 1993, 1997, true)
  DPSTEP(1, 1994, 1998, true)
  DPSTEP(2, 1995, 1999, true)
  DPSTEP(3, 1996, 0, false)
  DPSTEP(0, 1997, 0, false)
  DPSTEP(1, 1998, 0, false)
  DPSTEP(2, 1999, 0, false)

#undef LOADW
#undef DPSTEP
}

// ---------------- pi from consecutive mu rows (fully parallel) -----------
// pi[b,0,s] = (1,0); pi[b,t,s] = softmax([mu[t-1,s], mu[t-1,s-1]]), s-1<0 -> NEG
__global__ __launch_bounds__(256)
void pi_kernel(const float* __restrict__ mu, float* __restrict__ pi)
{
  const int gid = blockIdx.x * 256 + threadIdx.x;   // one float4 of mu-row per thread
  if (gid >= NMU / 4) return;
  const int b   = gid / (T_ * S_ / 4);
  const int rem = gid - b * (T_ * S_ / 4);
  const int t   = rem / (S_ / 4);
  const int s4  = rem - t * (S_ / 4);
  float* wp = pi + (size_t)gid * 8;
  if (t == 0) {
    *(float4*)wp       = make_float4(1.f, 0.f, 1.f, 0.f);
    *(float4*)(wp + 4) = make_float4(1.f, 0.f, 1.f, 0.f);
    return;
  }
  const float* row = mu + (size_t)b * T_ * S_ + (size_t)(t - 1) * S_;
  float4 v = *(const float4*)&row[4 * s4];
  float left = (s4 == 0) ? NEGV : row[4 * s4 - 1];
  float pv[4] = {v.x, v.y, v.z, v.w};
  float sf[4] = {left, v.x, v.y, v.z};
  float p0[4], p1[4];
#pragma unroll
  for (int i = 0; i < 4; i++) {
    float d = pv[i] - sf[i];
    float e = __expf(-fabsf(d));
    float q = 1.f + e;
    float r;
    asm("v_rcp_f32 %0, %1" : "=v"(r) : "v"(q));
    float rr = (d >= 0.f) ? r : 1.f - r;
    p0[i] = rr; p1[i] = 1.f - rr;
  }
  *(float4*)wp       = make_float4(p0[0], p1[0], p0[1], p1[1]);
  *(float4*)(wp + 4) = make_float4(p0[2], p1[2], p0[3], p1[3]);
}

// -------------------------------------------------------------------------
extern "C" void kernel_launch(void* const* d_in, const int* in_sizes, int n_in,
                              void* d_out, int out_size, void* d_ws, size_t ws_size,
                              hipStream_t stream)
{
  (void)in_sizes; (void)n_in; (void)out_size; (void)d_ws; (void)ws_size;
  const float* x   = (const float*)d_in[0];
  const float* enc = (const float*)d_in[1];
  const float* msk = (const float*)d_in[2];
  const float* w1  = (const float*)d_in[3];
  const float* b1  = (const float*)d_in[4];
  const float* w2  = (const float*)d_in[5];
  const float* b2  = (const float*)d_in[6];
  const float* w3  = (const float*)d_in[7];
  const float* b3  = (const float*)d_in[8];

  float* out = (float*)d_out;
  float* mu  = out;                       // [B,T,S]
  float* pi  = out + NMU;                 // [B,T,S,2]
  float* al  = out + NMU + NPI;           // [B,T,S]
  float* wsp = out + NMU + NPI + NMU;     // [B,T,H]
  float* h1  = pi;                        // conv scratch inside pi region
  float* h2  = pi + NWSP;
  float* wdp = pi;                        // DP weights scratch (pi written last)

  dim3 cgrid((T_ + 31) / 32, B_);
  hipLaunchKernelGGL((conv1d_tanh<C0_>), cgrid, dim3(256), 0, stream, x,  w1, b1, h1);
  hipLaunchKernelGGL((conv1d_tanh<H_>),  cgrid, dim3(256), 0, stream, h1, w2, b2, h2);
  hipLaunchKernelGGL((conv1d_tanh<H_>),  cgrid, dim3(256), 0, stream, h2, w3, b3, wsp);
  hipLaunchKernelGGL(einsum_ts, dim3((T_ + 127) / 128, (S_ + 63) / 64, B_), dim3(256),
                     0, stream, wsp, enc, al);
  hipLaunchKernelGGL(softmax_stats, dim3((S_ + 63) / 64, B_), dim3(256), 0, stream, al, mu);
  hipLaunchKernelGGL(norm_kernel, dim3(NMU / 4 / 256), dim3(256), 0, stream, al, msk, mu, wdp);
  hipLaunchKernelGGL(dp_mu4, dim3(2), dim3(1024), 0, stream, wdp, mu);
  hipLaunchKernelGGL(pi_kernel, dim3(NMU / 4 / 256), dim3(256), 0, stream, mu, pi);
}

// Round 8
// 3297.356 us; speedup vs baseline: 1.3077x; 1.3077x over previous
//
#include <hip/hip_runtime.h>
#include <hip/hip_bf16.h>

#define B_ 32
#define T_ 2000
#define S_ 400
#define C0_ 80
#define H_ 256

static constexpr float NEGV = -1e9f;
static constexpr int NMU  = B_ * T_ * S_;       // 25,600,000
static constexpr int NPI  = 2 * NMU;            // 51,200,000
static constexpr int NWSP = B_ * T_ * H_;       // 16,384,000

// ---------------- conv1d (K=5, SAME) + bias + tanh ----------------------
template<int CIN>
__global__ __launch_bounds__(256)
void conv1d_tanh(const float* __restrict__ x, const float* __restrict__ w,
                 const float* __restrict__ bias, float* __restrict__ y)
{
  constexpr int TT  = 32;        // t rows per block
  constexpr int JW  = TT + 4;    // halo rows (pad 2 each side)
  constexpr int STR = 40;        // padded LDS stride
  __shared__ float xs[CIN * STR];
  const int b   = blockIdx.y;
  const int t0  = blockIdx.x * TT;
  const int tid = threadIdx.x;
  const float* xb = x + (size_t)b * T_ * CIN;
  for (int idx = tid; idx < JW * CIN; idx += 256) {
    int ci = idx % CIN;
    int j  = idx / CIN;
    int t  = t0 - 2 + j;
    xs[ci * STR + j] = (t >= 0 && t < T_) ? xb[(size_t)t * CIN + ci] : 0.f;
  }
  __syncthreads();
  const int co = tid;
  float acc[TT];
#pragma unroll
  for (int i = 0; i < TT; i++) acc[i] = 0.f;
  for (int ci = 0; ci < CIN; ci++) {
    float xv[JW];
    const float4* xp = (const float4*)&xs[ci * STR];
#pragma unroll
    for (int r = 0; r < JW / 4; r++) {
      float4 q = xp[r];
      xv[4*r+0] = q.x; xv[4*r+1] = q.y; xv[4*r+2] = q.z; xv[4*r+3] = q.w;
    }
#pragma unroll
    for (int k = 0; k < 5; k++) {
      float wv = w[((size_t)k * CIN + ci) * H_ + co];
#pragma unroll
      for (int i = 0; i < TT; i++) acc[i] = fmaf(xv[i + k], wv, acc[i]);
    }
  }
  const float bv = bias[co];
#pragma unroll
  for (int i = 0; i < TT; i++) {
    int t = t0 + i;
    if (t < T_) y[((size_t)b * T_ + t) * H_ + co] = tanhf(acc[i] + bv);
  }
}

// ---------------- W[b,t,s] = sum_h Wspec[b,t,h] * src_enc[b,s,h] --------
__global__ __launch_bounds__(256)
void einsum_ts(const float* __restrict__ A, const float* __restrict__ E,
               float* __restrict__ Wg)
{
  constexpr int GT = 128, GS = 64, KC = 16;
  __shared__ float As[KC][GT + 4];
  __shared__ float Bs[KC][GS + 4];
  const int b   = blockIdx.z;
  const int t0  = blockIdx.x * GT;
  const int s0  = blockIdx.y * GS;
  const int tid = threadIdx.x;
  const int tx  = tid & 15;
  const int ty  = tid >> 4;
  float4 acc[8];
#pragma unroll
  for (int i = 0; i < 8; i++) acc[i] = make_float4(0.f, 0.f, 0.f, 0.f);
  const float* Ab = A + (size_t)b * T_ * H_;
  const float* Eb = E + (size_t)b * S_ * H_;
  for (int kc = 0; kc < H_; kc += KC) {
#pragma unroll
    for (int r = 0; r < 2; r++) {
      int f4  = tid + 256 * r;
      int row = f4 >> 2;
      int c4  = f4 & 3;
      int t   = t0 + row;
      float4 v = make_float4(0, 0, 0, 0);
      if (t < T_) v = *(const float4*)&Ab[(size_t)t * H_ + kc + c4 * 4];
      As[c4*4+0][row] = v.x; As[c4*4+1][row] = v.y;
      As[c4*4+2][row] = v.z; As[c4*4+3][row] = v.w;
    }
    {
      int row = tid >> 2;
      int c4  = tid & 3;
      int s   = s0 + row;
      float4 v = make_float4(0, 0, 0, 0);
      if (s < S_) v = *(const float4*)&Eb[(size_t)s * H_ + kc + c4 * 4];
      Bs[c4*4+0][row] = v.x; Bs[c4*4+1][row] = v.y;
      Bs[c4*4+2][row] = v.z; Bs[c4*4+3][row] = v.w;
    }
    __syncthreads();
#pragma unroll
    for (int kk = 0; kk < KC; kk++) {
      float4 a0 = *(const float4*)&As[kk][ty * 8];
      float4 a1 = *(const float4*)&As[kk][ty * 8 + 4];
      float4 bb = *(const float4*)&Bs[kk][tx * 4];
      float av[8] = {a0.x, a0.y, a0.z, a0.w, a1.x, a1.y, a1.z, a1.w};
#pragma unroll
      for (int i = 0; i < 8; i++) {
        acc[i].x = fmaf(av[i], bb.x, acc[i].x);
        acc[i].y = fmaf(av[i], bb.y, acc[i].y);
        acc[i].z = fmaf(av[i], bb.z, acc[i].z);
        acc[i].w = fmaf(av[i], bb.w, acc[i].w);
      }
    }
    __syncthreads();
  }
  float* Wb = Wg + (size_t)b * T_ * S_;
  const int s = s0 + tx * 4;
#pragma unroll
  for (int i = 0; i < 8; i++) {
    int t = t0 + ty * 8 + i;
    if (t < T_ && s < S_) *(float4*)&Wb[(size_t)t * S_ + s] = acc[i];
  }
}

// ---------------- per-(b,s) column softmax stats over T ------------------
// Writes M + ln(L) into mu[b][0][s] (consumed then overwritten by dp).
__global__ __launch_bounds__(256)
void softmax_stats(const float* __restrict__ Wg, float* __restrict__ statsOut)
{
  const int b  = blockIdx.y;
  const int tx = threadIdx.x & 63;
  const int ty = threadIdx.x >> 6;            // 0..3
  const int s  = blockIdx.x * 64 + tx;
  const bool act = (s < S_);
  float m = -1e30f, l = 0.f;
  if (act) {
    const float* col = Wg + (size_t)b * T_ * S_ + s;
#pragma unroll 4
    for (int t = ty; t < T_; t += 4) {
      float v  = col[(size_t)t * S_];
      float nm = fmaxf(m, v);
      l = l * __expf(m - nm) + __expf(v - nm);
      m = nm;
    }
  }
  __shared__ float rm[4][64], rl[4][64];
  rm[ty][tx] = m; rl[ty][tx] = l;
  __syncthreads();
  if (ty == 0 && act) {
    float M = rm[0][tx];
#pragma unroll
    for (int q = 1; q < 4; q++) M = fmaxf(M, rm[q][tx]);
    float L = 0.f;
#pragma unroll
    for (int q = 0; q < 4; q++) L += rl[q][tx] * __expf(rm[q][tx] - M);
    float* st = statsOut + (size_t)b * T_ * S_;
    st[s] = M + __logf(L);                    // single fused stat
  }
}

// ---------------- alignment normalize + mask premultiply -----------------
// al_out = exp(raw - stat);  Wdp = al_out * mask  (Wdp -> pi-region scratch)
__global__ __launch_bounds__(256)
void norm_kernel(float* __restrict__ al,           // in: raw scores; out: alignments
                 const float* __restrict__ Mk,     // mask
                 const float* __restrict__ muStat, // [B,T,S]; row 0 = M+lnL
                 float* __restrict__ Wdp)          // [B,T,S] scratch
{
  const int gid = blockIdx.x * 256 + threadIdx.x;   // one float4 per thread
  if (gid >= NMU / 4) return;
  const int b   = gid / (T_ * S_ / 4);
  const int rem = gid - b * (T_ * S_ / 4);
  const int s4  = rem % (S_ / 4);
  const float4 st4 = *(const float4*)&muStat[(size_t)b * T_ * S_ + 4 * s4];
  float4 r = ((const float4*)al)[gid];
  float4 k = ((const float4*)Mk)[gid];
  float4 a;
  a.x = __expf(r.x - st4.x);
  a.y = __expf(r.y - st4.y);
  a.z = __expf(r.z - st4.z);
  a.w = __expf(r.w - st4.w);
  ((float4*)al)[gid]  = a;
  ((float4*)Wdp)[gid] = make_float4(a.x * k.x, a.y * k.y, a.z * k.z, a.w * k.w);
}

// ---------------- monotonic-alignment DP: self-DMA LDS ring --------------
// 1 wave/batch, 32 blocks. The wave DMAs row t+5 into an 8-row LDS ring via
// global_load_lds (registerless -> cannot be sunk), gates consumption with
// exact counted s_waitcnt vmcnt(N) (4 vmem ops/step FIFO), and reads rows
// 1 ahead into registers via ds_read_b128 (~120cy worst-case exposure).
// Lane l owns s=8l..8l+7 (lanes 0..49 active), one __shfl_up per step.
__global__ __launch_bounds__(64, 1)
void dp_mu5(const float* __restrict__ Wdp,   // [B,T,S] = alignments * mask
            float* __restrict__ muOut)       // [B,T,S]
{
  __shared__ float ring[8 * S_];             // 8 rows x 1600 B = 12.8 KB
  const int b = blockIdx.x;
  const int l = threadIdx.x;                 // 0..63
  const int s0raw = l * 8;
  const bool act = (s0raw < S_);             // lanes 0..49
  const int c0 = act ? s0raw : (S_ - 8);

  const float* wb  = Wdp   + (size_t)b * T_ * S_;
  float*       mub = muOut + (size_t)b * T_ * S_;

  float m[8];
  float4 A0, A1, B0, B1;

#define DMAROW(row)                                                         \
  { const char* src_ = (const char*)(wb + (size_t)(row) * S_);              \
    char* dst_ = (char*)ring + (((row) & 7) * 1600);                        \
    __builtin_amdgcn_global_load_lds(                                       \
      (const __attribute__((address_space(1))) void*)(src_ + l * 16),       \
      (__attribute__((address_space(3))) void*)(dst_ + l * 16), 16, 0, 0);  \
    if (l < 36)                                                             \
      __builtin_amdgcn_global_load_lds(                                     \
        (const __attribute__((address_space(1))) void*)(src_ + 1024 + l*16),\
        (__attribute__((address_space(3))) void*)(dst_ + 1024 + l*16),      \
        16, 0, 0); }

#define VMWAIT(n) asm volatile("s_waitcnt vmcnt(" #n ")" ::: "memory");

#define DSREAD(row, LO, HI)                                                 \
  { const float* p_ = ring + (((row) & 7) * S_) + c0;                       \
    LO = *(const float4*)p_;  HI = *(const float4*)(p_ + 4); }

#define COMPUTE(LO, HI, t)                                                  \
  { float wj[8] = {LO.x,LO.y,LO.z,LO.w,HI.x,HI.y,HI.z,HI.w};                \
    float sh = __shfl_up(m[7], 1);                                          \
    if (l == 0) sh = NEGV;                                                  \
    _Pragma("unroll")                                                       \
    for (int j = 7; j >= 0; j--) {                                          \
      float prev = m[j];                                                    \
      float sft  = (j == 0) ? sh : m[j - 1];                                \
      float d    = prev - sft;                                              \
      float e    = __expf(-fabsf(d));                                       \
      float lg   = __logf(1.f + e);                                         \
      float hx   = fmaxf(prev, sft);                                        \
      m[j] = wj[j] + hx + lg;                                               \
    }                                                                       \
    if (act) {                                                              \
      float* wm_ = mub + (size_t)(t) * S_ + c0;                             \
      *(float4*)wm_       = make_float4(m[0],m[1],m[2],m[3]);               \
      *(float4*)(wm_ + 4) = make_float4(m[4],m[5],m[6],m[7]);               \
    } }

// step with DMA prefetch (main loop; t+5 <= 1999 guaranteed)
#define STEP(t, CLO, CHI, NLO, NHI, VMN)                                    \
  { DMAROW((t) + 5) VMWAIT(VMN) DSREAD((t) + 1, NLO, NHI)                   \
    COMPUTE(CLO, CHI, (t)) }
// tail step: no DMA, literal vmcnt
#define STEPND(t, CLO, CHI, NLO, NHI, VMN)                                  \
  { VMWAIT(VMN) DSREAD((t) + 1, NLO, NHI) COMPUTE(CLO, CHI, (t)) }

  // ---- prologue: DMA rows 0..5, drain, read row 0, base case, read row 1
  DMAROW(0) DMAROW(1) DMAROW(2) DMAROW(3) DMAROW(4) DMAROW(5)
  VMWAIT(0)
  DSREAD(0, A0, A1)
  {
    float wj[8] = {A0.x,A0.y,A0.z,A0.w,A1.x,A1.y,A1.z,A1.w};
#pragma unroll
    for (int j = 0; j < 8; j++) m[j] = wj[j] + ((c0 + j) == 0 ? 0.f : NEGV);
    if (act) {
      *(float4*)&mub[c0]     = make_float4(m[0],m[1],m[2],m[3]);
      *(float4*)&mub[c0 + 4] = make_float4(m[4],m[5],m[6],m[7]);
    }
  }
  DSREAD(1, B0, B1)

  // ---- main loop: steps t=1..1994 (odd consumes B, even consumes A) ----
  // vmcnt(16) is exact: 4 vmem ops/step x 4 steps between DMA(t+1) and use.
  for (int t = 1; t <= 1993; t += 2) {
    STEP(t,     B0, B1, A0, A1, 16)
    STEP(t + 1, A0, A1, B0, B1, 16)
  }
  // ---- tail: rows 1995..1999 (DMAs exhausted at step 1994) ----
  STEPND(1995, B0, B1, A0, A1, 14)
  STEPND(1996, A0, A1, B0, B1, 12)
  STEPND(1997, B0, B1, A0, A1, 10)
  STEPND(1998, A0, A1, B0, B1, 8)
  COMPUTE(B0, B1, 1999)

#undef DMAROW
#undef VMWAIT
#undef DSREAD
#undef COMPUTE
#undef STEP
#undef STEPND
}

// ---------------- pi from consecutive mu rows (fully parallel) -----------
// pi[b,0,s] = (1,0); pi[b,t,s] = softmax([mu[t-1,s], mu[t-1,s-1]]), s-1<0 -> NEG
__global__ __launch_bounds__(256)
void pi_kernel(const float* __restrict__ mu, float* __restrict__ pi)
{
  const int gid = blockIdx.x * 256 + threadIdx.x;   // one float4 of mu-row per thread
  if (gid >= NMU / 4) return;
  const int b   = gid / (T_ * S_ / 4);
  const int rem = gid - b * (T_ * S_ / 4);
  const int t   = rem / (S_ / 4);
  const int s4  = rem - t * (S_ / 4);
  float* wp = pi + (size_t)gid * 8;
  if (t == 0) {
    *(float4*)wp       = make_float4(1.f, 0.f, 1.f, 0.f);
    *(float4*)(wp + 4) = make_float4(1.f, 0.f, 1.f, 0.f);
    return;
  }
  const float* row = mu + (size_t)b * T_ * S_ + (size_t)(t - 1) * S_;
  float4 v = *(const float4*)&row[4 * s4];
  float left = (s4 == 0) ? NEGV : row[4 * s4 - 1];
  float pv[4] = {v.x, v.y, v.z, v.w};
  float sf[4] = {left, v.x, v.y, v.z};
  float p0[4], p1[4];
#pragma unroll
  for (int i = 0; i < 4; i++) {
    float d = pv[i] - sf[i];
    float e = __expf(-fabsf(d));
    float q = 1.f + e;
    float r;
    asm("v_rcp_f32 %0, %1" : "=v"(r) : "v"(q));
    float rr = (d >= 0.f) ? r : 1.f - r;
    p0[i] = rr; p1[i] = 1.f - rr;
  }
  *(float4*)wp       = make_float4(p0[0], p1[0], p0[1], p1[1]);
  *(float4*)(wp + 4) = make_float4(p0[2], p1[2], p0[3], p1[3]);
}

// -------------------------------------------------------------------------
extern "C" void kernel_launch(void* const* d_in, const int* in_sizes, int n_in,
                              void* d_out, int out_size, void* d_ws, size_t ws_size,
                              hipStream_t stream)
{
  (void)in_sizes; (void)n_in; (void)out_size; (void)d_ws; (void)ws_size;
  const float* x   = (const float*)d_in[0];
  const float* enc = (const float*)d_in[1];
  const float* msk = (const float*)d_in[2];
  const float* w1  = (const float*)d_in[3];
  const float* b1  = (const float*)d_in[4];
  const float* w2  = (const float*)d_in[5];
  const float* b2  = (const float*)d_in[6];
  const float* w3  = (const float*)d_in[7];
  const float* b3  = (const float*)d_in[8];

  float* out = (float*)d_out;
  float* mu  = out;                       // [B,T,S]
  float* pi  = out + NMU;                 // [B,T,S,2]
  float* al  = out + NMU + NPI;           // [B,T,S]
  float* wsp = out + NMU + NPI + NMU;     // [B,T,H]
  float* h1  = pi;                        // conv scratch inside pi region
  float* h2  = pi + NWSP;
  float* wdp = pi;                        // DP weights scratch (pi written last)

  dim3 cgrid((T_ + 31) / 32, B_);
  hipLaunchKernelGGL((conv1d_tanh<C0_>), cgrid, dim3(256), 0, stream, x,  w1, b1, h1);
  hipLaunchKernelGGL((conv1d_tanh<H_>),  cgrid, dim3(256), 0, stream, h1, w2, b2, h2);
  hipLaunchKernelGGL((conv1d_tanh<H_>),  cgrid, dim3(256), 0, stream, h2, w3, b3, wsp);
  hipLaunchKernelGGL(einsum_ts, dim3((T_ + 127) / 128, (S_ + 63) / 64, B_), dim3(256),
                     0, stream, wsp, enc, al);
  hipLaunchKernelGGL(softmax_stats, dim3((S_ + 63) / 64, B_), dim3(256), 0, stream, al, mu);
  hipLaunchKernelGGL(norm_kernel, dim3(NMU / 4 / 256), dim3(256), 0, stream, al, msk, mu, wdp);
  hipLaunchKernelGGL(dp_mu5, dim3(B_), dim3(64), 0, stream, wdp, mu);
  hipLaunchKernelGGL(pi_kernel, dim3(NMU / 4 / 256), dim3(256), 0, stream, mu, pi);
}

// Round 9
// 1476.125 us; speedup vs baseline: 2.9212x; 2.2338x over previous
//
#include <hip/hip_runtime.h>
#include <hip/hip_bf16.h>

#define B_ 32
#define T_ 2000
#define S_ 400
#define C0_ 80
#define H_ 256

static constexpr float NEGV = -1e9f;
static constexpr int NMU  = B_ * T_ * S_;       // 25,600,000
static constexpr int NPI  = 2 * NMU;            // 51,200,000

typedef _Float16 f16x8 __attribute__((ext_vector_type(8)));
typedef float    f32x4 __attribute__((ext_vector_type(4)));

// ---------------- weight repack: wcat[co][k*CPAD+ci] = w[k][ci][co] ------
__global__ __launch_bounds__(256)
void wprep(const float* __restrict__ w, _Float16* __restrict__ wcat,
           int CIN, int CPAD)
{
  const int tot = 256 * 5 * CPAD;
  int idx = blockIdx.x * 256 + threadIdx.x;
  if (idx >= tot) return;
  int co  = idx / (5 * CPAD);
  int rem = idx - co * (5 * CPAD);
  int k   = rem / CPAD;
  int ci  = rem - k * CPAD;
  float v = (ci < CIN) ? w[((size_t)k * CIN + ci) * H_ + co] : 0.f;
  wcat[idx] = (_Float16)v;
}

// ---------------- conv1d (K=5, SAME) + bias + tanh via f16 MFMA ----------
// Block: 64 t-rows x 256 co, 4 waves. Wave w: 4 t-tiles x 4 co-tiles
// (co = w*64..w*64+63). A = x-patches from LDS, B = Wcat rows from L2.
// mfma(X,Y) = X*Y^T for [16][K] row-major fragments.
template<int CIN, int CPAD, bool INF32, bool OUTF32>
__global__ __launch_bounds__(256)
void conv_mfma(const void* __restrict__ xin, const _Float16* __restrict__ wcat,
               const float* __restrict__ bias, void* __restrict__ yout)
{
  constexpr int KK  = 5 * CPAD;      // 480 / 1280
  constexpr int NS  = KK / 32;       // 15 / 40
  constexpr int STR = CPAD + 8;      // LDS row stride (2-way conflicts only)
  __shared__ _Float16 xs[68 * STR];
  const int b   = blockIdx.y;
  const int t0  = blockIdx.x * 64;
  const int tid = threadIdx.x;
  const int w   = tid >> 6;
  const int l   = tid & 63;

  // ---- stage x tile rows t0-2 .. t0+65 into [68][CPAD] (fp16) ----
  if constexpr (INF32) {
    const float* xb = (const float*)xin + (size_t)b * T_ * CIN;
    constexpr int NG = CPAD / 4;
    for (int idx = tid; idx < 68 * NG; idx += 256) {
      int j = idx / NG, g = idx - j * NG;
      int t = t0 - 2 + j;
      int c = g * 4;
      float4 v = make_float4(0.f, 0.f, 0.f, 0.f);
      if (t >= 0 && t < T_ && c < CIN) v = *(const float4*)&xb[(size_t)t * CIN + c];
      _Float16* d = &xs[j * STR + c];
      d[0] = (_Float16)v.x; d[1] = (_Float16)v.y;
      d[2] = (_Float16)v.z; d[3] = (_Float16)v.w;
    }
  } else {
    const _Float16* xb = (const _Float16*)xin + (size_t)b * T_ * CIN;
    constexpr int NG = CPAD / 8;
    for (int idx = tid; idx < 68 * NG; idx += 256) {
      int j = idx / NG, g = idx - j * NG;
      int t = t0 - 2 + j;
      f16x8 v = {(_Float16)0,(_Float16)0,(_Float16)0,(_Float16)0,
                 (_Float16)0,(_Float16)0,(_Float16)0,(_Float16)0};
      if (t >= 0 && t < T_) v = *(const f16x8*)&xb[(size_t)t * CIN + g * 8];
      *(f16x8*)&xs[j * STR + g * 8] = v;
    }
  }
  __syncthreads();

  const int lr = l & 15;
  const int lk = (l >> 4) * 8;

  f32x4 acc[4][4];
  const f32x4 zz = {0.f, 0.f, 0.f, 0.f};
#pragma unroll
  for (int i = 0; i < 4; i++)
#pragma unroll
    for (int j = 0; j < 4; j++) acc[i][j] = zz;

  const _Float16* wbase = wcat + (size_t)(w * 64 + lr) * KK + lk;

  for (int kk = 0; kk < NS; kk++) {
    const int p  = kk * 32;
    const int k  = p / CPAD;
    const int ci = p - k * CPAD;
    f16x8 a0 = *(const f16x8*)&xs[( 0 + lr + k) * STR + ci + lk];
    f16x8 a1 = *(const f16x8*)&xs[(16 + lr + k) * STR + ci + lk];
    f16x8 a2 = *(const f16x8*)&xs[(32 + lr + k) * STR + ci + lk];
    f16x8 a3 = *(const f16x8*)&xs[(48 + lr + k) * STR + ci + lk];
    f16x8 w0 = *(const f16x8*)&wbase[(size_t)( 0) * KK + p];
    f16x8 w1 = *(const f16x8*)&wbase[(size_t)(16) * KK + p];
    f16x8 w2 = *(const f16x8*)&wbase[(size_t)(32) * KK + p];
    f16x8 w3 = *(const f16x8*)&wbase[(size_t)(48) * KK + p];
    acc[0][0] = __builtin_amdgcn_mfma_f32_16x16x32_f16(a0, w0, acc[0][0], 0, 0, 0);
    acc[0][1] = __builtin_amdgcn_mfma_f32_16x16x32_f16(a0, w1, acc[0][1], 0, 0, 0);
    acc[0][2] = __builtin_amdgcn_mfma_f32_16x16x32_f16(a0, w2, acc[0][2], 0, 0, 0);
    acc[0][3] = __builtin_amdgcn_mfma_f32_16x16x32_f16(a0, w3, acc[0][3], 0, 0, 0);
    acc[1][0] = __builtin_amdgcn_mfma_f32_16x16x32_f16(a1, w0, acc[1][0], 0, 0, 0);
    acc[1][1] = __builtin_amdgcn_mfma_f32_16x16x32_f16(a1, w1, acc[1][1], 0, 0, 0);
    acc[1][2] = __builtin_amdgcn_mfma_f32_16x16x32_f16(a1, w2, acc[1][2], 0, 0, 0);
    acc[1][3] = __builtin_amdgcn_mfma_f32_16x16x32_f16(a1, w3, acc[1][3], 0, 0, 0);
    acc[2][0] = __builtin_amdgcn_mfma_f32_16x16x32_f16(a2, w0, acc[2][0], 0, 0, 0);
    acc[2][1] = __builtin_amdgcn_mfma_f32_16x16x32_f16(a2, w1, acc[2][1], 0, 0, 0);
    acc[2][2] = __builtin_amdgcn_mfma_f32_16x16x32_f16(a2, w2, acc[2][2], 0, 0, 0);
    acc[2][3] = __builtin_amdgcn_mfma_f32_16x16x32_f16(a2, w3, acc[2][3], 0, 0, 0);
    acc[3][0] = __builtin_amdgcn_mfma_f32_16x16x32_f16(a3, w0, acc[3][0], 0, 0, 0);
    acc[3][1] = __builtin_amdgcn_mfma_f32_16x16x32_f16(a3, w1, acc[3][1], 0, 0, 0);
    acc[3][2] = __builtin_amdgcn_mfma_f32_16x16x32_f16(a3, w2, acc[3][2], 0, 0, 0);
    acc[3][3] = __builtin_amdgcn_mfma_f32_16x16x32_f16(a3, w3, acc[3][3], 0, 0, 0);
  }

  // ---- epilogue: bias + tanh, store ----
#pragma unroll
  for (int ct = 0; ct < 4; ct++) {
    const int co = w * 64 + ct * 16 + lr;
    const float bv = bias[co];
#pragma unroll
    for (int tt = 0; tt < 4; tt++) {
#pragma unroll
      for (int r = 0; r < 4; r++) {
        const int t = t0 + tt * 16 + (l >> 4) * 4 + r;
        if (t < T_) {
          float v = tanhf(acc[tt][ct][r] + bv);
          if constexpr (OUTF32)
            ((float*)yout)[((size_t)b * T_ + t) * H_ + co] = v;
          else
            ((_Float16*)yout)[((size_t)b * T_ + t) * H_ + co] = (_Float16)v;
        }
      }
    }
  }
}

// ---------------- W[b,t,s] = sum_h Wspec[b,t,h] * src_enc[b,s,h] --------
__global__ __launch_bounds__(256)
void einsum_ts(const float* __restrict__ A, const float* __restrict__ E,
               float* __restrict__ Wg)
{
  constexpr int GT = 128, GS = 64, KC = 16;
  __shared__ float As[KC][GT + 4];
  __shared__ float Bs[KC][GS + 4];
  const int b   = blockIdx.z;
  const int t0  = blockIdx.x * GT;
  const int s0  = blockIdx.y * GS;
  const int tid = threadIdx.x;
  const int tx  = tid & 15;
  const int ty  = tid >> 4;
  float4 acc[8];
#pragma unroll
  for (int i = 0; i < 8; i++) acc[i] = make_float4(0.f, 0.f, 0.f, 0.f);
  const float* Ab = A + (size_t)b * T_ * H_;
  const float* Eb = E + (size_t)b * S_ * H_;
  for (int kc = 0; kc < H_; kc += KC) {
#pragma unroll
    for (int r = 0; r < 2; r++) {
      int f4  = tid + 256 * r;
      int row = f4 >> 2;
      int c4  = f4 & 3;
      int t   = t0 + row;
      float4 v = make_float4(0, 0, 0, 0);
      if (t < T_) v = *(const float4*)&Ab[(size_t)t * H_ + kc + c4 * 4];
      As[c4*4+0][row] = v.x; As[c4*4+1][row] = v.y;
      As[c4*4+2][row] = v.z; As[c4*4+3][row] = v.w;
    }
    {
      int row = tid >> 2;
      int c4  = tid & 3;
      int s   = s0 + row;
      float4 v = make_float4(0, 0, 0, 0);
      if (s < S_) v = *(const float4*)&Eb[(size_t)s * H_ + kc + c4 * 4];
      Bs[c4*4+0][row] = v.x; Bs[c4*4+1][row] = v.y;
      Bs[c4*4+2][row] = v.z; Bs[c4*4+3][row] = v.w;
    }
    __syncthreads();
#pragma unroll
    for (int kk = 0; kk < KC; kk++) {
      float4 a0 = *(const float4*)&As[kk][ty * 8];
      float4 a1 = *(const float4*)&As[kk][ty * 8 + 4];
      float4 bb = *(const float4*)&Bs[kk][tx * 4];
      float av[8] = {a0.x, a0.y, a0.z, a0.w, a1.x, a1.y, a1.z, a1.w};
#pragma unroll
      for (int i = 0; i < 8; i++) {
        acc[i].x = fmaf(av[i], bb.x, acc[i].x);
        acc[i].y = fmaf(av[i], bb.y, acc[i].y);
        acc[i].z = fmaf(av[i], bb.z, acc[i].z);
        acc[i].w = fmaf(av[i], bb.w, acc[i].w);
      }
    }
    __syncthreads();
  }
  float* Wb = Wg + (size_t)b * T_ * S_;
  const int s = s0 + tx * 4;
#pragma unroll
  for (int i = 0; i < 8; i++) {
    int t = t0 + ty * 8 + i;
    if (t < T_ && s < S_) *(float4*)&Wb[(size_t)t * S_ + s] = acc[i];
  }
}

// ---------------- per-(b,s) column softmax stats over T ------------------
__global__ __launch_bounds__(256)
void softmax_stats(const float* __restrict__ Wg, float* __restrict__ statsOut)
{
  const int b  = blockIdx.y;
  const int tx = threadIdx.x & 63;
  const int ty = threadIdx.x >> 6;            // 0..3
  const int s  = blockIdx.x * 64 + tx;
  const bool act = (s < S_);
  float m = -1e30f, l = 0.f;
  if (act) {
    const float* col = Wg + (size_t)b * T_ * S_ + s;
#pragma unroll 4
    for (int t = ty; t < T_; t += 4) {
      float v  = col[(size_t)t * S_];
      float nm = fmaxf(m, v);
      l = l * __expf(m - nm) + __expf(v - nm);
      m = nm;
    }
  }
  __shared__ float rm[4][64], rl[4][64];
  rm[ty][tx] = m; rl[ty][tx] = l;
  __syncthreads();
  if (ty == 0 && act) {
    float M = rm[0][tx];
#pragma unroll
    for (int q = 1; q < 4; q++) M = fmaxf(M, rm[q][tx]);
    float L = 0.f;
#pragma unroll
    for (int q = 0; q < 4; q++) L += rl[q][tx] * __expf(rm[q][tx] - M);
    float* st = statsOut + (size_t)b * T_ * S_;
    st[s] = M + __logf(L);                    // single fused stat
  }
}

// ---------------- alignment normalize + mask premultiply -----------------
__global__ __launch_bounds__(256)
void norm_kernel(float* __restrict__ al,
                 const float* __restrict__ Mk,
                 const float* __restrict__ muStat,
                 float* __restrict__ Wdp)
{
  const int gid = blockIdx.x * 256 + threadIdx.x;
  if (gid >= NMU / 4) return;
  const int b   = gid / (T_ * S_ / 4);
  const int rem = gid - b * (T_ * S_ / 4);
  const int s4  = rem % (S_ / 4);
  const float4 st4 = *(const float4*)&muStat[(size_t)b * T_ * S_ + 4 * s4];
  float4 r = ((const float4*)al)[gid];
  float4 k = ((const float4*)Mk)[gid];
  float4 a;
  a.x = __expf(r.x - st4.x);
  a.y = __expf(r.y - st4.y);
  a.z = __expf(r.z - st4.z);
  a.w = __expf(r.w - st4.w);
  ((float4*)al)[gid]  = a;
  ((float4*)Wdp)[gid] = make_float4(a.x * k.x, a.y * k.y, a.z * k.z, a.w * k.w);
}

// ---------------- monotonic-alignment DP: mu only (round-4, 824us) -------
__global__ __launch_bounds__(64, 1)
void dp_mu(const float* __restrict__ Wdp, float* __restrict__ muOut)
{
  const int b = blockIdx.x;
  const int l = threadIdx.x;
  const int s0raw = l * 8;
  const bool act = (s0raw < S_);
  const int c0 = act ? s0raw : (S_ - 8);

  const float* wb  = Wdp   + (size_t)b * T_ * S_;
  float*       mub = muOut + (size_t)b * T_ * S_;

  float m[8];
  {
    float4 lo = *(const float4*)&wb[c0];
    float4 hi = *(const float4*)&wb[c0 + 4];
    float w0[8] = {lo.x,lo.y,lo.z,lo.w,hi.x,hi.y,hi.z,hi.w};
#pragma unroll
    for (int j = 0; j < 8; j++) m[j] = w0[j] + ((c0 + j) == 0 ? 0.f : NEGV);
    if (act) {
      *(float4*)&mub[c0]     = make_float4(m[0],m[1],m[2],m[3]);
      *(float4*)&mub[c0 + 4] = make_float4(m[4],m[5],m[6],m[7]);
    }
  }

  float4 wL[4], wH[4];

#define LOADW(slot, row)                                                    \
  { const float* r_ = wb + (size_t)(row) * S_ + c0;                         \
    wL[slot] = *(const float4*)r_;  wH[slot] = *(const float4*)(r_ + 4); }

#define DPSTEP(slot, t, prow, doPF)                                         \
  { float wj[8] = {wL[slot].x,wL[slot].y,wL[slot].z,wL[slot].w,             \
                   wH[slot].x,wH[slot].y,wH[slot].z,wH[slot].w};            \
    if (doPF) LOADW(slot, prow)                                             \
    float sh = __shfl_up(m[7], 1);                                          \
    if (l == 0) sh = NEGV;                                                  \
    _Pragma("unroll")                                                       \
    for (int j = 7; j >= 0; j--) {                                          \
      float prev = m[j];                                                    \
      float sft  = (j == 0) ? sh : m[j - 1];                                \
      float d    = prev - sft;                                              \
      float e    = __expf(-fabsf(d));                                       \
      float lg   = __logf(1.f + e);                                         \
      float hi   = fmaxf(prev, sft);                                        \
      m[j] = wj[j] + hi + lg;                                               \
    }                                                                       \
    if (act) {                                                              \
      float* wm_ = mub + (size_t)(t) * S_ + c0;                             \
      *(float4*)wm_       = make_float4(m[0],m[1],m[2],m[3]);               \
      *(float4*)(wm_ + 4) = make_float4(m[4],m[5],m[6],m[7]);               \
    } }

  LOADW(0, 1) LOADW(1, 2) LOADW(2, 3) LOADW(3, 4)

  int t0 = 1;
  for (; t0 + 7 <= T_ - 1; t0 += 4) {
    DPSTEP(0, t0 + 0, t0 + 4, true)
    DPSTEP(1, t0 + 1, t0 + 5, true)
    DPSTEP(2, t0 + 2, t0 + 6, true)
    DPSTEP(3, t0 + 3, t0 + 7, true)
  }
  DPSTEP(0, 1993, 1997, true)
  DPSTEP(1, 1994, 1998, true)
  DPSTEP(2, 1995, 1999, true)
  DPSTEP(3, 1996, 0, false)
  DPSTEP(0, 1997, 0, false)
  DPSTEP(1, 1998, 0, false)
  DPSTEP(2, 1999, 0, false)

#undef LOADW
#undef DPSTEP
}

// ---------------- pi from consecutive mu rows (fully parallel) -----------
__global__ __launch_bounds__(256)
void pi_kernel(const float* __restrict__ mu, float* __restrict__ pi)
{
  const int gid = blockIdx.x * 256 + threadIdx.x;
  if (gid >= NMU / 4) return;
  const int b   = gid / (T_ * S_ / 4);
  const int rem = gid - b * (T_ * S_ / 4);
  const int t   = rem / (S_ / 4);
  const int s4  = rem - t * (S_ / 4);
  float* wp = pi + (size_t)gid * 8;
  if (t == 0) {
    *(float4*)wp       = make_float4(1.f, 0.f, 1.f, 0.f);
    *(float4*)(wp + 4) = make_float4(1.f, 0.f, 1.f, 0.f);
    return;
  }
  const float* row = mu + (size_t)b * T_ * S_ + (size_t)(t - 1) * S_;
  float4 v = *(const float4*)&row[4 * s4];
  float left = (s4 == 0) ? NEGV : row[4 * s4 - 1];
  float pv[4] = {v.x, v.y, v.z, v.w};
  float sf[4] = {left, v.x, v.y, v.z};
  float p0[4], p1[4];
#pragma unroll
  for (int i = 0; i < 4; i++) {
    float d = pv[i] - sf[i];
    float e = __expf(-fabsf(d));
    float q = 1.f + e;
    float r;
    asm("v_rcp_f32 %0, %1" : "=v"(r) : "v"(q));
    float rr = (d >= 0.f) ? r : 1.f - r;
    p0[i] = rr; p1[i] = 1.f - rr;
  }
  *(float4*)wp       = make_float4(p0[0], p1[0], p0[1], p1[1]);
  *(float4*)(wp + 4) = make_float4(p0[2], p1[2], p0[3], p1[3]);
}

// -------------------------------------------------------------------------
extern "C" void kernel_launch(void* const* d_in, const int* in_sizes, int n_in,
                              void* d_out, int out_size, void* d_ws, size_t ws_size,
                              hipStream_t stream)
{
  (void)in_sizes; (void)n_in; (void)out_size; (void)d_ws; (void)ws_size;
  const float* x   = (const float*)d_in[0];
  const float* enc = (const float*)d_in[1];
  const float* msk = (const float*)d_in[2];
  const float* w1  = (const float*)d_in[3];
  const float* b1  = (const float*)d_in[4];
  const float* w2  = (const float*)d_in[5];
  const float* b2  = (const float*)d_in[6];
  const float* w3  = (const float*)d_in[7];
  const float* b3  = (const float*)d_in[8];

  float* out = (float*)d_out;
  float* mu  = out;                       // [B,T,S]
  float* pi  = out + NMU;                 // [B,T,S,2]
  float* al  = out + NMU + NPI;           // [B,T,S]
  float* wsp = out + NMU + NPI + NMU;     // [B,T,H] fp32

  // scratch inside pi region (pi written last, overwrites everything)
  float*     wdp = pi;                               // 25.6M floats
  _Float16*  h1  = (_Float16*)(pi + 26000000);       // 16.384M halves
  _Float16*  h2  = (_Float16*)(pi + 35000000);       // 16.384M halves
  _Float16*  wc1 = (_Float16*)(pi + 44000000);       // 256*480 halves
  _Float16*  wc2 = (_Float16*)(pi + 44100000);       // 256*1280 halves
  _Float16*  wc3 = (_Float16*)(pi + 44300000);       // 256*1280 halves

  // weight repack (fp32 -> fp16, co-major with k*CPAD+ci columns)
  hipLaunchKernelGGL(wprep, dim3((256*5*96 +255)/256), dim3(256), 0, stream, w1, wc1, C0_, 96);
  hipLaunchKernelGGL(wprep, dim3((256*5*256+255)/256), dim3(256), 0, stream, w2, wc2, H_, 256);
  hipLaunchKernelGGL(wprep, dim3((256*5*256+255)/256), dim3(256), 0, stream, w3, wc3, H_, 256);

  dim3 cgrid((T_ + 63) / 64, B_);
  hipLaunchKernelGGL((conv_mfma<C0_,  96, true,  false>), cgrid, dim3(256), 0, stream,
                     (const void*)x,  wc1, b1, (void*)h1);
  hipLaunchKernelGGL((conv_mfma<H_,  256, false, false>), cgrid, dim3(256), 0, stream,
                     (const void*)h1, wc2, b2, (void*)h2);
  hipLaunchKernelGGL((conv_mfma<H_,  256, false, true >), cgrid, dim3(256), 0, stream,
                     (const void*)h2, wc3, b3, (void*)wsp);

  hipLaunchKernelGGL(einsum_ts, dim3((T_ + 127) / 128, (S_ + 63) / 64, B_), dim3(256),
                     0, stream, wsp, enc, al);
  hipLaunchKernelGGL(softmax_stats, dim3((S_ + 63) / 64, B_), dim3(256), 0, stream, al, mu);
  hipLaunchKernelGGL(norm_kernel, dim3(NMU / 4 / 256), dim3(256), 0, stream, al, msk, mu, wdp);
  hipLaunchKernelGGL(dp_mu, dim3(B_), dim3(64), 0, stream, wdp, mu);
  hipLaunchKernelGGL(pi_kernel, dim3(NMU / 4 / 256), dim3(256), 0, stream, mu, pi);
}